// Round 5
// baseline (295.858 us; speedup 1.0000x reference)
//
#include <hip/hip_runtime.h>

#define N_NODES 100000
#define N_EDGES 6400000
#define D 12

#define SLOG 7
#define SSZ  128                           // nodes per bucket
#define NB   ((N_NODES + SSZ - 1) / SSZ)   // 782 buckets
#define SBLK 256                           // count/place blocks
#define STHR 512
#define SEPB (N_EDGES / SBLK)              // 25000 edges per block (exact)
#define RSTR 13                            // fallback agg row stride

#define CAP  2048                          // edges per chunk in agg pass
#define EPT  (CAP / 256)                   // 8 edges per thread per chunk

// ---- bf16 helpers ----------------------------------------------------------
__device__ __forceinline__ unsigned int f2bf(float f) {
    unsigned int u = __float_as_uint(f);
    return (u + 0x7fffu + ((u >> 16) & 1u)) >> 16;   // RTNE
}
__device__ __forceinline__ unsigned int pk2(float lo, float hi) {
    return (f2bf(hi) << 16) | f2bf(lo);
}
__device__ __forceinline__ float bflo(unsigned int u) { return __uint_as_float(u << 16); }
__device__ __forceinline__ float bfhi(unsigned int u) { return __uint_as_float(u & 0xffff0000u); }

// Prep: fp32 x [N,12] -> bf16 xb padded rows of 16 elems (32 B, 3.2 MB total).
__global__ __launch_bounds__(256) void prep_kernel(
    const float* __restrict__ x, unsigned int* __restrict__ xb)
{
    int i = blockIdx.x * 256 + threadIdx.x;
    if (i >= N_NODES) return;
    const float4* xr = (const float4*)(x) + (size_t)i * 3;
    float4 a = xr[0], b = xr[1], c = xr[2];
    unsigned int* o = xb + (size_t)i * 8;
    ((uint4*)o)[0] = make_uint4(pk2(a.x, a.y), pk2(a.z, a.w), pk2(b.x, b.y), pk2(b.z, b.w));
    ((uint2*)(o + 4))[0] = make_uint2(pk2(c.x, c.y), pk2(c.z, c.w));
}

// Pass 1: per-block LDS histogram -> cnt[block][bucket] matrix (plain stores,
// no global atomics, no memset needed). nt loads: dei is stream-once.
__global__ __launch_bounds__(512) void count_kernel(
    const int* __restrict__ ei, int* __restrict__ cnt)
{
    __shared__ int h[NB];
    int t = threadIdx.x;
    for (int i = t; i < NB; i += STHR) h[i] = 0;
    __syncthreads();
    const int* dei = ei + N_EDGES;
    int start = blockIdx.x * SEPB;
    int end = start + SEPB;
    int e = start + t;
    while (e + 3 * STHR < end) {
        int d0 = __builtin_nontemporal_load(&dei[e]);
        int d1 = __builtin_nontemporal_load(&dei[e + STHR]);
        int d2 = __builtin_nontemporal_load(&dei[e + 2 * STHR]);
        int d3 = __builtin_nontemporal_load(&dei[e + 3 * STHR]);
        atomicAdd(&h[d0 >> SLOG], 1);
        atomicAdd(&h[d1 >> SLOG], 1);
        atomicAdd(&h[d2 >> SLOG], 1);
        atomicAdd(&h[d3 >> SLOG], 1);
        e += 4 * STHR;
    }
    while (e < end) {
        int d = __builtin_nontemporal_load(&dei[e]);
        atomicAdd(&h[d >> SLOG], 1);
        e += STHR;
    }
    __syncthreads();
    int* row = cnt + (size_t)blockIdx.x * NB;
    for (int i = t; i < NB; i += STHR) row[i] = h[i];
}

// Pass 2: single block. Column-sum cnt -> bucket totals -> scan -> base[],
// then per-bucket running prefix over blocks -> blockcur[block][bucket].
// 8-deep manual ILP so the strided L2 loads pipeline.
__global__ __launch_bounds__(1024) void scan2_kernel(
    const int* __restrict__ cnt, int* __restrict__ base, int* __restrict__ blockcur)
{
    __shared__ int buf[1024];
    int tid = threadIdx.x;
    int tot = 0;
    if (tid < NB) {
        int s0 = 0, s1 = 0, s2 = 0, s3 = 0, s4 = 0, s5 = 0, s6 = 0, s7 = 0;
        for (int b = 0; b < SBLK; b += 8) {
            s0 += cnt[(size_t)(b + 0) * NB + tid];
            s1 += cnt[(size_t)(b + 1) * NB + tid];
            s2 += cnt[(size_t)(b + 2) * NB + tid];
            s3 += cnt[(size_t)(b + 3) * NB + tid];
            s4 += cnt[(size_t)(b + 4) * NB + tid];
            s5 += cnt[(size_t)(b + 5) * NB + tid];
            s6 += cnt[(size_t)(b + 6) * NB + tid];
            s7 += cnt[(size_t)(b + 7) * NB + tid];
        }
        tot = ((s0 + s1) + (s2 + s3)) + ((s4 + s5) + (s6 + s7));
    }
    buf[tid] = (tid < NB) ? tot : 0;
    __syncthreads();
    for (int o = 1; o < 1024; o <<= 1) {
        int v = (tid >= o) ? buf[tid - o] : 0;
        __syncthreads();
        buf[tid] += v;
        __syncthreads();
    }
    int excl = buf[tid] - tot;
    if (tid < NB) base[tid] = excl;
    if (tid == 0) base[NB] = N_EDGES;
    if (tid < NB) {
        int run = excl;
        for (int b0 = 0; b0 < SBLK; b0 += 8) {
            int c[8];
#pragma unroll
            for (int i = 0; i < 8; ++i) c[i] = cnt[(size_t)(b0 + i) * NB + tid];
#pragma unroll
            for (int i = 0; i < 8; ++i) {
                blockcur[(size_t)(b0 + i) * NB + tid] = run;
                run += c[i];
            }
        }
    }
}

// Pass 3: place edges into reserved per-(block,bucket) runs.
// Cursors come preloaded from blockcur (no global cursor atomics).
// nt loads on ei keep L2 free for the open write lines.
__global__ __launch_bounds__(512) void place_kernel(
    const int* __restrict__ ei, const int* __restrict__ blockcur,
    unsigned int* __restrict__ sorted)
{
    __shared__ int h[NB];
    int t = threadIdx.x;
    const int* row = blockcur + (size_t)blockIdx.x * NB;
    for (int i = t; i < NB; i += STHR) h[i] = row[i];
    __syncthreads();
    const int* dei = ei + N_EDGES;
    int start = blockIdx.x * SEPB;
    int end = start + SEPB;
    int e = start + t;
    while (e + 3 * STHR < end) {
        int s0 = __builtin_nontemporal_load(&ei[e]);
        int s1 = __builtin_nontemporal_load(&ei[e + STHR]);
        int s2 = __builtin_nontemporal_load(&ei[e + 2 * STHR]);
        int s3 = __builtin_nontemporal_load(&ei[e + 3 * STHR]);
        int d0 = __builtin_nontemporal_load(&dei[e]);
        int d1 = __builtin_nontemporal_load(&dei[e + STHR]);
        int d2 = __builtin_nontemporal_load(&dei[e + 2 * STHR]);
        int d3 = __builtin_nontemporal_load(&dei[e + 3 * STHR]);
        int p0 = atomicAdd(&h[d0 >> SLOG], 1);
        int p1 = atomicAdd(&h[d1 >> SLOG], 1);
        int p2 = atomicAdd(&h[d2 >> SLOG], 1);
        int p3 = atomicAdd(&h[d3 >> SLOG], 1);
        sorted[p0] = ((unsigned)s0 << SLOG) | (unsigned)(d0 & (SSZ - 1));
        sorted[p1] = ((unsigned)s1 << SLOG) | (unsigned)(d1 & (SSZ - 1));
        sorted[p2] = ((unsigned)s2 << SLOG) | (unsigned)(d2 & (SSZ - 1));
        sorted[p3] = ((unsigned)s3 << SLOG) | (unsigned)(d3 & (SSZ - 1));
        e += 4 * STHR;
    }
    while (e < end) {
        int s = __builtin_nontemporal_load(&ei[e]);
        int d = __builtin_nontemporal_load(&dei[e]);
        int pos = atomicAdd(&h[d >> SLOG], 1);
        sorted[pos] = ((unsigned)s << SLOG) | (unsigned)(d & (SSZ - 1));
        e += STHR;
    }
}

// Pass 4: register accumulation, 2 LDS atomics/edge.
// Per chunk: count -> block-scan segment bases -> place gathered bf16 rows into
// per-node LDS segments -> 2 threads per node accumulate in registers.
__global__ __launch_bounds__(256) void agg_reg_kernel(
    const unsigned int* __restrict__ sorted, const int* __restrict__ base,
    const unsigned int* __restrict__ xb,
    const float* __restrict__ x, const float* __restrict__ Wl,
    const float* __restrict__ Wr, const float* __restrict__ bias,
    float* __restrict__ out)
{
    __shared__ float sWl[D * D], sWr[D * D], sb[D];
    __shared__ int cnt[SSZ];
    __shared__ int sbuf[SSZ];          // scan workspace
    __shared__ int segbase[SSZ + 1];
    __shared__ int cursor[SSZ];
    __shared__ int cnt_tot[SSZ];
    __shared__ unsigned vals[CAP * 6]; // 48 KB; reused as red[] at the end

    int t = threadIdx.x;
    int b = blockIdx.x;

    if (t < D * D) { sWl[t] = Wl[t]; sWr[t] = Wr[t]; }
    if (t < D) sb[t] = bias[t];
    if (t < SSZ) cnt_tot[t] = 0;

    float acc[D];
#pragma unroll
    for (int d = 0; d < D; ++d) acc[d] = 0.f;

    int loc = t >> 1;       // node owned in accumulate phase (2 thr/node)
    int sub = t & 1;

    int start = base[b];
    int end = base[b + 1];

    for (int c0 = start; c0 < end; c0 += CAP) {
        int n = min(CAP, end - c0);
        if (t < SSZ) cnt[t] = 0;
        __syncthreads();

        // Load my packed edges into registers (coalesced, nt), then count.
        unsigned pe[EPT];
        int ne = 0;
        for (int j = t; j < n; j += 256) pe[ne++] = __builtin_nontemporal_load(&sorted[c0 + j]);
#pragma unroll
        for (int k = 0; k < EPT; ++k)
            if (k < ne) atomicAdd(&cnt[pe[k] & (SSZ - 1)], 1);
        __syncthreads();

        // Block-wide Hillis-Steele scan of 128 counters.
        if (t < SSZ) sbuf[t] = cnt[t];
        __syncthreads();
        for (int o = 1; o < SSZ; o <<= 1) {
            int v = (t < SSZ && t >= o) ? sbuf[t - o] : 0;
            __syncthreads();
            if (t < SSZ) sbuf[t] += v;
            __syncthreads();
        }
        if (t < SSZ) {
            segbase[t + 1] = sbuf[t];
            if (t == 0) segbase[0] = 0;
        }
        __syncthreads();
        if (t < SSZ) { cursor[t] = segbase[t]; cnt_tot[t] += cnt[t]; }
        __syncthreads();

        // Place: gather bf16 row, write into this node's LDS segment.
#pragma unroll
        for (int k = 0; k < EPT; ++k) {
            if (k < ne) {
                unsigned p = pe[k];
                int slot = atomicAdd(&cursor[p & (SSZ - 1)], 1);
                const unsigned* r = xb + (size_t)(p >> SLOG) * 8;
                uint2 q0 = ((const uint2*)r)[0];
                uint2 q1 = ((const uint2*)r)[1];
                uint2 q2 = ((const uint2*)r)[2];
                unsigned* vv = &vals[slot * 6];
                ((uint2*)vv)[0] = q0;      // 8B-aligned (24B slots)
                ((uint2*)vv)[1] = q1;
                ((uint2*)vv)[2] = q2;
            }
        }
        __syncthreads();

        // Accumulate: thread (loc, sub) scans its node's segment, registers only.
        int s0 = segbase[loc], s1 = segbase[loc + 1];
        for (int j = s0 + sub; j < s1; j += 2) {
            const unsigned* vv = &vals[j * 6];
            uint2 q0 = ((const uint2*)vv)[0];
            uint2 q1 = ((const uint2*)vv)[1];
            uint2 q2 = ((const uint2*)vv)[2];
            acc[0]  += bflo(q0.x); acc[1]  += bfhi(q0.x);
            acc[2]  += bflo(q0.y); acc[3]  += bfhi(q0.y);
            acc[4]  += bflo(q1.x); acc[5]  += bfhi(q1.x);
            acc[6]  += bflo(q1.y); acc[7]  += bfhi(q1.y);
            acc[8]  += bflo(q2.x); acc[9]  += bfhi(q2.x);
            acc[10] += bflo(q2.y); acc[11] += bfhi(q2.y);
        }
        __syncthreads();   // before next chunk reuses cnt/vals
    }

    // Reduce the 2 partials per node via LDS overlay (stride 13, odd vs 32 banks).
    float* red = (float*)vals;   // needs 2*1664 = 3328 floats <= CAP*6 = 12288
#pragma unroll
    for (int d = 0; d < D; ++d) red[sub * 1664 + loc * 13 + d] = acc[d];
    __syncthreads();

    if (t < SSZ) {
        int node = b * SSZ + t;
        if (node < N_NODES) {
            float m[D];
#pragma unroll
            for (int d = 0; d < D; ++d)
                m[d] = red[t * 13 + d] + red[1664 + t * 13 + d];
            float inv = 1.f / fmaxf((float)cnt_tot[t], 1.f);
#pragma unroll
            for (int d = 0; d < D; ++d) m[d] *= inv;

            float xi[D];
            const float4* xr = (const float4*)(x) + (size_t)node * 3;
            float4 x0 = xr[0], x1 = xr[1], x2 = xr[2];
            xi[0] = x0.x; xi[1] = x0.y; xi[2]  = x0.z; xi[3]  = x0.w;
            xi[4] = x1.x; xi[5] = x1.y; xi[6]  = x1.z; xi[7]  = x1.w;
            xi[8] = x2.x; xi[9] = x2.y; xi[10] = x2.z; xi[11] = x2.w;

            float o[D];
#pragma unroll
            for (int oo = 0; oo < D; ++oo) {
                float a = sb[oo];
#pragma unroll
                for (int d = 0; d < D; ++d) {
                    a += m[d] * sWl[oo * D + d];
                    a += xi[d] * sWr[oo * D + d];
                }
                o[oo] = a;
            }
            float4* orow = (float4*)(out) + (size_t)node * 3;
            orow[0] = make_float4(o[0], o[1], o[2], o[3]);
            orow[1] = make_float4(o[4], o[5], o[6], o[7]);
            orow[2] = make_float4(o[8], o[9], o[10], o[11]);
        }
    }
}

// Mid-tier agg (fp32 gather + LDS atomics) — used if ws is tight.
__global__ __launch_bounds__(256) void agg_finalize_f32_kernel(
    const unsigned int* __restrict__ sorted, const int* __restrict__ base,
    const float* __restrict__ x, const float* __restrict__ Wl,
    const float* __restrict__ Wr, const float* __restrict__ bias,
    float* __restrict__ out)
{
    __shared__ float agg[SSZ * RSTR];
    __shared__ float sWl[D * D], sWr[D * D], sb[D];
    int t = threadIdx.x;
    int b = blockIdx.x;
    for (int i = t; i < SSZ * RSTR; i += 256) agg[i] = 0.f;
    if (t < D * D) { sWl[t] = Wl[t]; sWr[t] = Wr[t]; }
    if (t < D) sb[t] = bias[t];
    __syncthreads();
    int start = base[b];
    int end = base[b + 1];
    for (int e = start + t; e < end; e += 256) {
        unsigned p = sorted[e];
        int src = (int)(p >> SLOG);
        int lc = (int)(p & (SSZ - 1));
        const float4* xr = (const float4*)(x) + (size_t)src * 3;
        float4 a = xr[0], b4 = xr[1], c = xr[2];
        float* ar = &agg[lc * RSTR];
        atomicAdd(ar + 0,  a.x);  atomicAdd(ar + 1,  a.y);
        atomicAdd(ar + 2,  a.z);  atomicAdd(ar + 3,  a.w);
        atomicAdd(ar + 4,  b4.x); atomicAdd(ar + 5,  b4.y);
        atomicAdd(ar + 6,  b4.z); atomicAdd(ar + 7,  b4.w);
        atomicAdd(ar + 8,  c.x);  atomicAdd(ar + 9,  c.y);
        atomicAdd(ar + 10, c.z);  atomicAdd(ar + 11, c.w);
        atomicAdd(ar + 12, 1.f);
    }
    __syncthreads();
    if (t < SSZ) {
        int node = b * SSZ + t;
        if (node < N_NODES) {
            const float* ar = &agg[t * RSTR];
            float inv = 1.f / fmaxf(ar[12], 1.f);
            float m[D], xi[D];
#pragma unroll
            for (int d = 0; d < D; ++d) m[d] = ar[d] * inv;
            const float4* xr = (const float4*)(x) + (size_t)node * 3;
            float4 x0 = xr[0], x1 = xr[1], x2 = xr[2];
            xi[0] = x0.x; xi[1] = x0.y; xi[2]  = x0.z; xi[3]  = x0.w;
            xi[4] = x1.x; xi[5] = x1.y; xi[6]  = x1.z; xi[7]  = x1.w;
            xi[8] = x2.x; xi[9] = x2.y; xi[10] = x2.z; xi[11] = x2.w;
            float o[D];
#pragma unroll
            for (int oo = 0; oo < D; ++oo) {
                float a = sb[oo];
#pragma unroll
                for (int d = 0; d < D; ++d) {
                    a += m[d] * sWl[oo * D + d];
                    a += xi[d] * sWr[oo * D + d];
                }
                o[oo] = a;
            }
            float4* orow = (float4*)(out) + (size_t)node * 3;
            orow[0] = make_float4(o[0], o[1], o[2], o[3]);
            orow[1] = make_float4(o[4], o[5], o[6], o[7]);
            orow[2] = make_float4(o[8], o[9], o[10], o[11]);
        }
    }
}

// ---------------- Last-resort fallback: global atomics ----------------------

__global__ __launch_bounds__(256) void scatter_kernel(
    const int* __restrict__ ei, const float* __restrict__ x,
    float* __restrict__ agg, float* __restrict__ cnt)
{
    int e = blockIdx.x * blockDim.x + threadIdx.x;
    if (e >= N_EDGES) return;
    int src = ei[e];
    int dst = ei[N_EDGES + e];
    const float4* xr = (const float4*)(x + (size_t)src * D);
    float4 a = xr[0], b4 = xr[1], c = xr[2];
    float* dr = agg + (size_t)dst * D;
    atomicAdd(dr + 0,  a.x);  atomicAdd(dr + 1,  a.y);
    atomicAdd(dr + 2,  a.z);  atomicAdd(dr + 3,  a.w);
    atomicAdd(dr + 4,  b4.x); atomicAdd(dr + 5,  b4.y);
    atomicAdd(dr + 6,  b4.z); atomicAdd(dr + 7,  b4.w);
    atomicAdd(dr + 8,  c.x);  atomicAdd(dr + 9,  c.y);
    atomicAdd(dr + 10, c.z);  atomicAdd(dr + 11, c.w);
    atomicAdd(cnt + dst, 1.0f);
}

__global__ __launch_bounds__(256) void finalize_kernel(
    const float* __restrict__ x, const float* __restrict__ Wl,
    const float* __restrict__ Wr, const float* __restrict__ bias,
    const float* __restrict__ agg, const float* __restrict__ cnt,
    float* __restrict__ out)
{
    __shared__ float sWl[D * D], sWr[D * D], sb[D];
    int t = threadIdx.x;
    if (t < D * D) { sWl[t] = Wl[t]; sWr[t] = Wr[t]; }
    if (t < D) sb[t] = bias[t];
    __syncthreads();
    int i = blockIdx.x * blockDim.x + t;
    if (i >= N_NODES) return;
    float inv = 1.0f / fmaxf(cnt[i], 1.0f);
    float m[D], xi[D];
    const float4* ar = (const float4*)(agg + (size_t)i * D);
    const float4* xr = (const float4*)(x + (size_t)i * D);
    float4 a0 = ar[0], a1 = ar[1], a2 = ar[2];
    float4 x0 = xr[0], x1 = xr[1], x2 = xr[2];
    m[0] = a0.x * inv; m[1] = a0.y * inv; m[2]  = a0.z * inv; m[3]  = a0.w * inv;
    m[4] = a1.x * inv; m[5] = a1.y * inv; m[6]  = a1.z * inv; m[7]  = a1.w * inv;
    m[8] = a2.x * inv; m[9] = a2.y * inv; m[10] = a2.z * inv; m[11] = a2.w * inv;
    xi[0] = x0.x; xi[1] = x0.y; xi[2]  = x0.z; xi[3]  = x0.w;
    xi[4] = x1.x; xi[5] = x1.y; xi[6]  = x1.z; xi[7]  = x1.w;
    xi[8] = x2.x; xi[9] = x2.y; xi[10] = x2.z; xi[11] = x2.w;
    float o[D];
#pragma unroll
    for (int oo = 0; oo < D; ++oo) {
        float acc = sb[oo];
#pragma unroll
        for (int d = 0; d < D; ++d) {
            acc += m[d] * sWl[oo * D + d];
            acc += xi[d] * sWr[oo * D + d];
        }
        o[oo] = acc;
    }
    float4* orow = (float4*)(out + (size_t)i * D);
    orow[0] = make_float4(o[0], o[1], o[2], o[3]);
    orow[1] = make_float4(o[4], o[5], o[6], o[7]);
    orow[2] = make_float4(o[8], o[9], o[10], o[11]);
}

extern "C" void kernel_launch(void* const* d_in, const int* in_sizes, int n_in,
                              void* d_out, int out_size, void* d_ws, size_t ws_size,
                              hipStream_t stream) {
    const float* x    = (const float*)d_in[0];
    const float* Wl   = (const float*)d_in[1];
    const float* Wr   = (const float*)d_in[2];
    const float* bias = (const float*)d_in[3];
    const int*   ei   = (const int*)d_in[4];
    float* out = (float*)d_out;

    size_t sortedBytes   = (size_t)N_EDGES * sizeof(unsigned int);     // 25.6 MB
    size_t xbBytes       = (size_t)N_NODES * 8 * sizeof(unsigned int); // 3.2 MB
    size_t cntBytes      = (size_t)SBLK * NB * sizeof(int);            // 0.8 MB
    size_t blockcurBytes = cntBytes;                                   // 0.8 MB
    size_t baseBytes     = (size_t)(NB + 1) * sizeof(int);
    size_t neededFull = sortedBytes + xbBytes + cntBytes + blockcurBytes + baseBytes;
    size_t neededMid  = sortedBytes + cntBytes + blockcurBytes + baseBytes;
    size_t neededLast = ((size_t)N_NODES * D + N_NODES) * sizeof(float);

    if (ws_size >= neededFull) {
        char* p = (char*)d_ws;
        unsigned int* sorted = (unsigned int*)p;        p += sortedBytes;
        unsigned int* xb     = (unsigned int*)p;        p += xbBytes;
        int* cnt      = (int*)p;                        p += cntBytes;
        int* blockcur = (int*)p;                        p += blockcurBytes;
        int* base     = (int*)p;

        prep_kernel<<<(N_NODES + 255) / 256, 256, 0, stream>>>(x, xb);
        count_kernel<<<SBLK, STHR, 0, stream>>>(ei, cnt);
        scan2_kernel<<<1, 1024, 0, stream>>>(cnt, base, blockcur);
        place_kernel<<<SBLK, STHR, 0, stream>>>(ei, blockcur, sorted);
        agg_reg_kernel<<<NB, 256, 0, stream>>>(sorted, base, xb, x, Wl, Wr, bias, out);
    } else if (ws_size >= neededMid) {
        char* p = (char*)d_ws;
        unsigned int* sorted = (unsigned int*)p;        p += sortedBytes;
        int* cnt      = (int*)p;                        p += cntBytes;
        int* blockcur = (int*)p;                        p += blockcurBytes;
        int* base     = (int*)p;

        count_kernel<<<SBLK, STHR, 0, stream>>>(ei, cnt);
        scan2_kernel<<<1, 1024, 0, stream>>>(cnt, base, blockcur);
        place_kernel<<<SBLK, STHR, 0, stream>>>(ei, blockcur, sorted);
        agg_finalize_f32_kernel<<<NB, 256, 0, stream>>>(sorted, base, x, Wl, Wr, bias, out);
    } else {
        float* agg = (float*)d_ws;
        float* cnt = agg + (size_t)N_NODES * D;
        hipMemsetAsync(d_ws, 0, neededLast, stream);
        scatter_kernel<<<(N_EDGES + 255) / 256, 256, 0, stream>>>(ei, x, agg, cnt);
        finalize_kernel<<<(N_NODES + 255) / 256, 256, 0, stream>>>(x, Wl, Wr, bias, agg, cnt, out);
    }
}

// Round 6
// 287.273 us; speedup vs baseline: 1.0299x; 1.0299x over previous
//
#include <hip/hip_runtime.h>

#define N_NODES 100000
#define N_EDGES 6400000
#define D 12

#define SLOG 7
#define SSZ  128                           // nodes per bucket
#define NB   ((N_NODES + SSZ - 1) / SSZ)   // 782 buckets
#define SBLK 256                           // partition blocks
#define STHR 512
#define SEPB (N_EDGES / SBLK)              // 25000 edges per block (exact)
#define RSTR 13

#define CAP  1792                          // edges per chunk in agg pass (42KB)
#define EPT  (CAP / 256)                   // 7 edges per thread per chunk

// ---- bf16 helpers ----------------------------------------------------------
__device__ __forceinline__ unsigned int f2bf(float f) {
    unsigned int u = __float_as_uint(f);
    return (u + 0x7fffu + ((u >> 16) & 1u)) >> 16;   // RTNE
}
__device__ __forceinline__ unsigned int pk2(float lo, float hi) {
    return (f2bf(hi) << 16) | f2bf(lo);
}
__device__ __forceinline__ float bflo(unsigned int u) { return __uint_as_float(u << 16); }
__device__ __forceinline__ float bfhi(unsigned int u) { return __uint_as_float(u & 0xffff0000u); }

// Prep: fp32 x [N,12] -> bf16 xb padded rows of 16 elems (32 B, 3.2 MB total).
__global__ __launch_bounds__(256) void prep_kernel(
    const float* __restrict__ x, unsigned int* __restrict__ xb)
{
    int i = blockIdx.x * 256 + threadIdx.x;
    if (i >= N_NODES) return;
    const float4* xr = (const float4*)(x) + (size_t)i * 3;
    float4 a = xr[0], b = xr[1], c = xr[2];
    unsigned int* o = xb + (size_t)i * 8;
    ((uint4*)o)[0] = make_uint4(pk2(a.x, a.y), pk2(a.z, a.w), pk2(b.x, b.y), pk2(b.z, b.w));
    ((uint2*)(o + 4))[0] = make_uint2(pk2(c.x, c.y), pk2(c.z, c.w));
}

// Partition: block-major output. Each block bucket-sorts its own 25000-edge
// range into its own contiguous region sorted[b*SEPB .. ). Writes stream at
// amp ~1.0 (100KB window, L2-resident until fully dirty). Emits per-block
// metadata: cnt[b][k] (bucket counts) and rowpre[b][k] (in-block bucket start).
// Phase A: count dst (cold read). In-block scan. Phase B: re-read (L3-hot),
// place via local cursor atomic. No cross-block coordination anywhere.
__global__ __launch_bounds__(512) void part_kernel(
    const int* __restrict__ ei, int* __restrict__ cnt, int* __restrict__ rowpre,
    unsigned int* __restrict__ sorted)
{
    __shared__ int h[NB];
    __shared__ int cur[NB];
    __shared__ int sb2[512];
    int t = threadIdx.x;
    int b = blockIdx.x;
    for (int i = t; i < NB; i += STHR) h[i] = 0;
    __syncthreads();

    const int* dei = ei + N_EDGES;
    int start = b * SEPB;
    int end = start + SEPB;

    // Phase A: histogram of dst buckets.
    int e = start + t;
    while (e + 3 * STHR < end) {
        int d0 = dei[e], d1 = dei[e + STHR], d2 = dei[e + 2 * STHR], d3 = dei[e + 3 * STHR];
        atomicAdd(&h[d0 >> SLOG], 1);
        atomicAdd(&h[d1 >> SLOG], 1);
        atomicAdd(&h[d2 >> SLOG], 1);
        atomicAdd(&h[d3 >> SLOG], 1);
        e += 4 * STHR;
    }
    while (e < end) { atomicAdd(&h[dei[e] >> SLOG], 1); e += STHR; }
    __syncthreads();

    // Save counts row.
    int* crow = cnt + (size_t)b * NB;
    for (int i = t; i < NB; i += STHR) crow[i] = h[i];

    // In-block exclusive scan of h -> cur (pairs + 512-wide Hillis-Steele).
    int pairv = 0;
    if (t < (NB + 1) / 2) {
        pairv = h[2 * t] + ((2 * t + 1 < NB) ? h[2 * t + 1] : 0);
    }
    sb2[t] = pairv;
    __syncthreads();
    for (int o = 1; o < 512; o <<= 1) {
        int v = (t >= o) ? sb2[t - o] : 0;
        __syncthreads();
        sb2[t] += v;
        __syncthreads();
    }
    if (t < (NB + 1) / 2) {
        int excl = sb2[t] - pairv;
        cur[2 * t] = excl;
        if (2 * t + 1 < NB) cur[2 * t + 1] = excl + h[2 * t];
    }
    __syncthreads();

    // Save in-block bucket starts.
    int* rrow = rowpre + (size_t)b * NB;
    for (int i = t; i < NB; i += STHR) rrow[i] = cur[i];
    __syncthreads();

    // Phase B: place into own region (re-read ei, L3-hot dst / cold src).
    unsigned int* dst = sorted + (size_t)b * SEPB;
    e = start + t;
    while (e + 3 * STHR < end) {
        int s0 = ei[e], s1 = ei[e + STHR], s2 = ei[e + 2 * STHR], s3 = ei[e + 3 * STHR];
        int d0 = dei[e], d1 = dei[e + STHR], d2 = dei[e + 2 * STHR], d3 = dei[e + 3 * STHR];
        int p0 = atomicAdd(&cur[d0 >> SLOG], 1);
        int p1 = atomicAdd(&cur[d1 >> SLOG], 1);
        int p2 = atomicAdd(&cur[d2 >> SLOG], 1);
        int p3 = atomicAdd(&cur[d3 >> SLOG], 1);
        dst[p0] = ((unsigned)s0 << SLOG) | (unsigned)(d0 & (SSZ - 1));
        dst[p1] = ((unsigned)s1 << SLOG) | (unsigned)(d1 & (SSZ - 1));
        dst[p2] = ((unsigned)s2 << SLOG) | (unsigned)(d2 & (SSZ - 1));
        dst[p3] = ((unsigned)s3 << SLOG) | (unsigned)(d3 & (SSZ - 1));
        e += 4 * STHR;
    }
    while (e < end) {
        int s = ei[e], d = dei[e];
        int pos = atomicAdd(&cur[d >> SLOG], 1);
        dst[pos] = ((unsigned)s << SLOG) | (unsigned)(d & (SSZ - 1));
        e += STHR;
    }
}

// Agg: one block per bucket. Bucket's edges live in 256 per-block segments;
// walk them as one virtual stream via a 256-entry prefix table + binary search.
// Then the proven register-accumulation machinery (2 LDS atomics/edge).
__global__ __launch_bounds__(256) void agg_reg_kernel(
    const unsigned int* __restrict__ sorted, const int* __restrict__ cntm,
    const int* __restrict__ rowpre, const unsigned int* __restrict__ xb,
    const float* __restrict__ x, const float* __restrict__ Wl,
    const float* __restrict__ Wr, const float* __restrict__ bias,
    float* __restrict__ out)
{
    __shared__ float sWl[D * D], sWr[D * D], sb[D];
    __shared__ int cnt[SSZ];
    __shared__ int sbuf[SSZ];
    __shared__ int segbase[SSZ + 1];
    __shared__ int cursor[SSZ];
    __shared__ int cnt_tot[SSZ];
    __shared__ int seglen[SBLK];
    __shared__ int segoff[SBLK];        // global start of segment in sorted[]
    __shared__ int segpre[SBLK + 1];    // prefix of seglen (virtual stream)
    __shared__ unsigned vals[CAP * 6];  // 42 KB; reused as red[] at the end

    int t = threadIdx.x;
    int k = blockIdx.x;                 // bucket id

    if (t < D * D) { sWl[t] = Wl[t]; sWr[t] = Wr[t]; }
    if (t < D) sb[t] = bias[t];
    if (t < SSZ) cnt_tot[t] = 0;

    // Load this bucket's segment table (column k of cnt/rowpre matrices).
    if (t < SBLK) {
        seglen[t] = cntm[(size_t)t * NB + k];
        segoff[t] = t * SEPB + rowpre[(size_t)t * NB + k];
    }
    __syncthreads();
    // Prefix over 256 segments.
    int sl = (t < SBLK) ? seglen[t] : 0;
    if (t < SBLK) sbuf[0] = 0;  // dummy to keep compiler quiet (sbuf reused later)
    {
        // Hillis-Steele on segpre using segpre[] as workspace.
        if (t < SBLK) segpre[t + 1] = sl;
        if (t == 0) segpre[0] = 0;
        __syncthreads();
        for (int o = 1; o < SBLK; o <<= 1) {
            int v = 0;
            if (t < SBLK && (int)t + 1 > o) v = segpre[t + 1 - o];
            __syncthreads();
            if (t < SBLK) segpre[t + 1] += v;
            __syncthreads();
        }
    }
    int T = segpre[SBLK];

    float acc[D];
#pragma unroll
    for (int d = 0; d < D; ++d) acc[d] = 0.f;

    int loc = t >> 1;       // node owned in accumulate phase (2 thr/node)
    int sub = t & 1;

    for (int c0 = 0; c0 < T; c0 += CAP) {
        int n = min(CAP, T - c0);
        if (t < SSZ) cnt[t] = 0;
        __syncthreads();

        // Load my packed edges via virtual-index walk (binary search segpre).
        unsigned pe[EPT];
        int ne = 0;
        for (int j = t; j < n; j += 256) {
            int v = c0 + j;
            int lo = 0, hi = SBLK;
            while (hi - lo > 1) {
                int mid = (lo + hi) >> 1;
                if (segpre[mid] <= v) lo = mid; else hi = mid;
            }
            int gi = segoff[lo] + (v - segpre[lo]);
            pe[ne++] = sorted[gi];
        }
#pragma unroll
        for (int q = 0; q < EPT; ++q)
            if (q < ne) atomicAdd(&cnt[pe[q] & (SSZ - 1)], 1);
        __syncthreads();

        // Block-wide Hillis-Steele scan of 128 counters.
        if (t < SSZ) sbuf[t] = cnt[t];
        __syncthreads();
        for (int o = 1; o < SSZ; o <<= 1) {
            int v = (t < SSZ && t >= o) ? sbuf[t - o] : 0;
            __syncthreads();
            if (t < SSZ) sbuf[t] += v;
            __syncthreads();
        }
        if (t < SSZ) {
            segbase[t + 1] = sbuf[t];
            if (t == 0) segbase[0] = 0;
        }
        __syncthreads();
        if (t < SSZ) { cursor[t] = segbase[t]; cnt_tot[t] += cnt[t]; }
        __syncthreads();

        // Place: gather bf16 row, write into this node's LDS segment.
#pragma unroll
        for (int q = 0; q < EPT; ++q) {
            if (q < ne) {
                unsigned p = pe[q];
                int slot = atomicAdd(&cursor[p & (SSZ - 1)], 1);
                const unsigned* r = xb + (size_t)(p >> SLOG) * 8;
                uint2 q0 = ((const uint2*)r)[0];
                uint2 q1 = ((const uint2*)r)[1];
                uint2 q2 = ((const uint2*)r)[2];
                unsigned* vv = &vals[slot * 6];
                ((uint2*)vv)[0] = q0;
                ((uint2*)vv)[1] = q1;
                ((uint2*)vv)[2] = q2;
            }
        }
        __syncthreads();

        // Accumulate: thread (loc, sub) scans its node's segment, registers only.
        int s0 = segbase[loc], s1 = segbase[loc + 1];
        for (int j = s0 + sub; j < s1; j += 2) {
            const unsigned* vv = &vals[j * 6];
            uint2 q0 = ((const uint2*)vv)[0];
            uint2 q1 = ((const uint2*)vv)[1];
            uint2 q2 = ((const uint2*)vv)[2];
            acc[0]  += bflo(q0.x); acc[1]  += bfhi(q0.x);
            acc[2]  += bflo(q0.y); acc[3]  += bfhi(q0.y);
            acc[4]  += bflo(q1.x); acc[5]  += bfhi(q1.x);
            acc[6]  += bflo(q1.y); acc[7]  += bfhi(q1.y);
            acc[8]  += bflo(q2.x); acc[9]  += bfhi(q2.x);
            acc[10] += bflo(q2.y); acc[11] += bfhi(q2.y);
        }
        __syncthreads();   // before next chunk reuses cnt/vals
    }

    // Reduce the 2 partials per node via LDS overlay (stride 13 vs 32 banks).
    float* red = (float*)vals;   // needs 2*1664 = 3328 floats <= CAP*6 = 10752
#pragma unroll
    for (int d = 0; d < D; ++d) red[sub * 1664 + loc * 13 + d] = acc[d];
    __syncthreads();

    if (t < SSZ) {
        int node = k * SSZ + t;
        if (node < N_NODES) {
            float m[D];
#pragma unroll
            for (int d = 0; d < D; ++d)
                m[d] = red[t * 13 + d] + red[1664 + t * 13 + d];
            float inv = 1.f / fmaxf((float)cnt_tot[t], 1.f);
#pragma unroll
            for (int d = 0; d < D; ++d) m[d] *= inv;

            float xi[D];
            const float4* xr = (const float4*)(x) + (size_t)node * 3;
            float4 x0 = xr[0], x1 = xr[1], x2 = xr[2];
            xi[0] = x0.x; xi[1] = x0.y; xi[2]  = x0.z; xi[3]  = x0.w;
            xi[4] = x1.x; xi[5] = x1.y; xi[6]  = x1.z; xi[7]  = x1.w;
            xi[8] = x2.x; xi[9] = x2.y; xi[10] = x2.z; xi[11] = x2.w;

            float o[D];
#pragma unroll
            for (int oo = 0; oo < D; ++oo) {
                float a = sb[oo];
#pragma unroll
                for (int d = 0; d < D; ++d) {
                    a += m[d] * sWl[oo * D + d];
                    a += xi[d] * sWr[oo * D + d];
                }
                o[oo] = a;
            }
            float4* orow = (float4*)(out) + (size_t)node * 3;
            orow[0] = make_float4(o[0], o[1], o[2], o[3]);
            orow[1] = make_float4(o[4], o[5], o[6], o[7]);
            orow[2] = make_float4(o[8], o[9], o[10], o[11]);
        }
    }
}

// ---------------- Last-resort fallback: global atomics ----------------------

__global__ __launch_bounds__(256) void scatter_kernel(
    const int* __restrict__ ei, const float* __restrict__ x,
    float* __restrict__ agg, float* __restrict__ cnt)
{
    int e = blockIdx.x * blockDim.x + threadIdx.x;
    if (e >= N_EDGES) return;
    int src = ei[e];
    int dst = ei[N_EDGES + e];
    const float4* xr = (const float4*)(x + (size_t)src * D);
    float4 a = xr[0], b4 = xr[1], c = xr[2];
    float* dr = agg + (size_t)dst * D;
    atomicAdd(dr + 0,  a.x);  atomicAdd(dr + 1,  a.y);
    atomicAdd(dr + 2,  a.z);  atomicAdd(dr + 3,  a.w);
    atomicAdd(dr + 4,  b4.x); atomicAdd(dr + 5,  b4.y);
    atomicAdd(dr + 6,  b4.z); atomicAdd(dr + 7,  b4.w);
    atomicAdd(dr + 8,  c.x);  atomicAdd(dr + 9,  c.y);
    atomicAdd(dr + 10, c.z);  atomicAdd(dr + 11, c.w);
    atomicAdd(cnt + dst, 1.0f);
}

__global__ __launch_bounds__(256) void finalize_kernel(
    const float* __restrict__ x, const float* __restrict__ Wl,
    const float* __restrict__ Wr, const float* __restrict__ bias,
    const float* __restrict__ agg, const float* __restrict__ cnt,
    float* __restrict__ out)
{
    __shared__ float sWl[D * D], sWr[D * D], sb[D];
    int t = threadIdx.x;
    if (t < D * D) { sWl[t] = Wl[t]; sWr[t] = Wr[t]; }
    if (t < D) sb[t] = bias[t];
    __syncthreads();
    int i = blockIdx.x * blockDim.x + t;
    if (i >= N_NODES) return;
    float inv = 1.0f / fmaxf(cnt[i], 1.0f);
    float m[D], xi[D];
    const float4* ar = (const float4*)(agg + (size_t)i * D);
    const float4* xr = (const float4*)(x + (size_t)i * D);
    float4 a0 = ar[0], a1 = ar[1], a2 = ar[2];
    float4 x0 = xr[0], x1 = xr[1], x2 = xr[2];
    m[0] = a0.x * inv; m[1] = a0.y * inv; m[2]  = a0.z * inv; m[3]  = a0.w * inv;
    m[4] = a1.x * inv; m[5] = a1.y * inv; m[6]  = a1.z * inv; m[7]  = a1.w * inv;
    m[8] = a2.x * inv; m[9] = a2.y * inv; m[10] = a2.z * inv; m[11] = a2.w * inv;
    xi[0] = x0.x; xi[1] = x0.y; xi[2]  = x0.z; xi[3]  = x0.w;
    xi[4] = x1.x; xi[5] = x1.y; xi[6]  = x1.z; xi[7]  = x1.w;
    xi[8] = x2.x; xi[9] = x2.y; xi[10] = x2.z; xi[11] = x2.w;
    float o[D];
#pragma unroll
    for (int oo = 0; oo < D; ++oo) {
        float acc = sb[oo];
#pragma unroll
        for (int d = 0; d < D; ++d) {
            acc += m[d] * sWl[oo * D + d];
            acc += xi[d] * sWr[oo * D + d];
        }
        o[oo] = acc;
    }
    float4* orow = (float4*)(out + (size_t)i * D);
    orow[0] = make_float4(o[0], o[1], o[2], o[3]);
    orow[1] = make_float4(o[4], o[5], o[6], o[7]);
    orow[2] = make_float4(o[8], o[9], o[10], o[11]);
}

extern "C" void kernel_launch(void* const* d_in, const int* in_sizes, int n_in,
                              void* d_out, int out_size, void* d_ws, size_t ws_size,
                              hipStream_t stream) {
    const float* x    = (const float*)d_in[0];
    const float* Wl   = (const float*)d_in[1];
    const float* Wr   = (const float*)d_in[2];
    const float* bias = (const float*)d_in[3];
    const int*   ei   = (const int*)d_in[4];
    float* out = (float*)d_out;

    size_t sortedBytes = (size_t)N_EDGES * sizeof(unsigned int);     // 25.6 MB
    size_t xbBytes     = (size_t)N_NODES * 8 * sizeof(unsigned int); // 3.2 MB
    size_t cntBytes    = (size_t)SBLK * NB * sizeof(int);            // 0.8 MB
    size_t rowpreBytes = cntBytes;                                   // 0.8 MB
    size_t neededFull = sortedBytes + xbBytes + cntBytes + rowpreBytes;
    size_t neededLast = ((size_t)N_NODES * D + N_NODES) * sizeof(float);

    if (ws_size >= neededFull) {
        char* p = (char*)d_ws;
        unsigned int* sorted = (unsigned int*)p;        p += sortedBytes;
        unsigned int* xb     = (unsigned int*)p;        p += xbBytes;
        int* cnt    = (int*)p;                          p += cntBytes;
        int* rowpre = (int*)p;

        prep_kernel<<<(N_NODES + 255) / 256, 256, 0, stream>>>(x, xb);
        part_kernel<<<SBLK, STHR, 0, stream>>>(ei, cnt, rowpre, sorted);
        agg_reg_kernel<<<NB, 256, 0, stream>>>(sorted, cnt, rowpre, xb, x, Wl, Wr, bias, out);
    } else {
        float* agg = (float*)d_ws;
        float* cnt = agg + (size_t)N_NODES * D;
        hipMemsetAsync(d_ws, 0, neededLast, stream);
        scatter_kernel<<<(N_EDGES + 255) / 256, 256, 0, stream>>>(ei, x, agg, cnt);
        finalize_kernel<<<(N_NODES + 255) / 256, 256, 0, stream>>>(x, Wl, Wr, bias, agg, cnt, out);
    }
}